// Round 9
// baseline (127.208 us; speedup 1.0000x reference)
//
#include <hip/hip_runtime.h>
#include <math.h>

#define B 2
#define V 6
#define C 256
#define Q 900
#define NH 8
#define HD 32
#define RADIUS 2.0f
#define M_ROWS (B * Q)   // 1800
#define NT 29            // ceil(900/32) key tiles
#define SPLITS 8
#define TPS 4            // tiles per split (last split gets 1)
#define RBH (B * NH * Q) // 14400 rows per split

using short8 = __attribute__((ext_vector_type(8))) short;  // 8 bf16
using f32x4  = __attribute__((ext_vector_type(4))) float;

// f32 -> bf16 (RNE), bit pattern in a short
__device__ __forceinline__ short f2bf(float f) {
    union { float f; unsigned u; } x; x.f = f;
    unsigned r = x.u + 0x7fffu + ((x.u >> 16) & 1u);
    return (short)(r >> 16);
}

// Build a bf16 B-fragment for mfma_16x16x32 directly from fp32 W[n][k0..k0+7].
__device__ __forceinline__ short8 loadWfrag(const float* __restrict__ W, int n, int k0) {
    float4 a = *(const float4*)(W + (size_t)n * C + k0);
    float4 b = *(const float4*)(W + (size_t)n * C + k0 + 4);
    short8 s;
    s[0] = f2bf(a.x); s[1] = f2bf(a.y); s[2] = f2bf(a.z); s[3] = f2bf(a.w);
    s[4] = f2bf(b.x); s[5] = f2bf(b.y); s[6] = f2bf(b.z); s[7] = f2bf(b.w);
    return s;
}

// keypoints: [0,0,0],[R,0,0],[0,R,0],[-R,0,0]
__device__ __forceinline__ float kpx(int k) { return (k == 1) ? RADIUS : ((k == 3) ? -RADIUS : 0.f); }
__device__ __forceinline__ float kpy(int k) { return (k == 2) ? RADIUS : 0.f; }

// MFMA GEMM body, BM=64/BN=64, 256 threads, weights loaded fp32 on the fly.
__device__ void mgemm64_body(const float* __restrict__ A,
                             const float* __restrict__ W,
                             const float* __restrict__ bias,
                             float* __restrict__ Y,
                             int m0, int n0t)
{
    __shared__ __align__(16) short As[64][264];
    const int tid = threadIdx.x;
    const int lane = tid & 63, w = tid >> 6;
    const int l15 = lane & 15, g = lane >> 4;

    {
        int r = tid & 63, part = tid >> 6;
        int gm = m0 + r;
        #pragma unroll
        for (int c = 0; c < 8; ++c) {
            int k = part * 64 + c * 8;
            float4 x = make_float4(0.f, 0.f, 0.f, 0.f);
            float4 y = make_float4(0.f, 0.f, 0.f, 0.f);
            if (gm < M_ROWS) {
                x = *(const float4*)(A + (size_t)gm * C + k);
                y = *(const float4*)(A + (size_t)gm * C + k + 4);
            }
            short8 s;
            s[0] = f2bf(x.x); s[1] = f2bf(x.y); s[2] = f2bf(x.z); s[3] = f2bf(x.w);
            s[4] = f2bf(y.x); s[5] = f2bf(y.y); s[6] = f2bf(y.z); s[7] = f2bf(y.w);
            *(short8*)&As[r][k] = s;
        }
    }
    __syncthreads();

    f32x4 acc[4];
    #pragma unroll
    for (int c = 0; c < 4; ++c) acc[c] = (f32x4){0.f, 0.f, 0.f, 0.f};

    #pragma unroll
    for (int ks = 0; ks < 8; ++ks) {
        short8 af = *(const short8*)&As[16 * w + l15][ks * 32 + 8 * g];
        #pragma unroll
        for (int c = 0; c < 4; ++c) {
            int nt = n0t * 4 + c;
            short8 bf = loadWfrag(W, nt * 16 + l15, ks * 32 + 8 * g);
            acc[c] = __builtin_amdgcn_mfma_f32_16x16x32_bf16(af, bf, acc[c], 0, 0, 0);
        }
    }

    #pragma unroll
    for (int c = 0; c < 4; ++c) {
        int n = n0t * 64 + c * 16 + l15;
        float bv = bias[n];
        #pragma unroll
        for (int j = 0; j < 4; ++j) {
            int gm = m0 + 16 * w + 4 * g + j;
            if (gm < M_ROWS) Y[(size_t)gm * C + n] = acc[c][j] + bv;
        }
    }
}

// Fused: blocks [0,1800) = sampler; blocks [1800,1916) = Q projection.
__global__ __launch_bounds__(256)
void sampler_qproj(const float* __restrict__ f0, const float* __restrict__ f1,
                   const float* __restrict__ refs, const float* __restrict__ intr,
                   const float* __restrict__ extr, float* __restrict__ sampled,
                   const float* __restrict__ qin, const float* __restrict__ Wq,
                   const float* __restrict__ bq, float* __restrict__ qbuf)
{
    const int bid = blockIdx.x;
    if (bid >= B * Q) {
        int idx = bid - B * Q;
        mgemm64_body(qin, Wq, bq, qbuf, (idx >> 2) * 64, idx & 3);
        return;
    }

    int b = bid / Q, q = bid % Q;
    int t = threadIdx.x;
    __shared__ float sx0[2][24], sy0[2][24], swx1[2][24], swy1[2][24];
    __shared__ float sval[24];

    if (t < 48) {
        int lvl = t / 24, pt = t % 24;
        int v = pt >> 2, kp = pt & 3;
        const float* r = refs + (size_t)(b * Q + q) * 3;
        float px = r[0] + kpx(kp), py = r[1] + kpy(kp), pz = r[2];
        const float* E = extr + (size_t)(b * V + v) * 16;
        float cx = E[0] * px + E[1] * py + E[2]  * pz + E[3];
        float cy = E[4] * px + E[5] * py + E[6]  * pz + E[7];
        float cz = E[8] * px + E[9] * py + E[10] * pz + E[11];
        const float* Km = intr + (size_t)(b * V + v) * 9;
        float u = Km[0] * cx + Km[1] * cy + Km[2] * cz;
        float w = Km[3] * cx + Km[4] * cy + Km[5] * cz;
        float z = Km[6] * cx + Km[7] * cy + Km[8] * cz;
        float zs = (fabsf(z) > 1e-6f) ? z : 1e-6f;
        float ru = u / zs, rv = w / zs;
        const float Wf = lvl ? 87.f : 175.f;   // W-1
        const float Hf = lvl ? 31.f : 63.f;    // H-1
        float gx = 2.f * ru / Wf - 1.f;
        float gy = 2.f * rv / Hf - 1.f;
        float x = (gx + 1.f) * 0.5f * Wf;
        float y = (gy + 1.f) * 0.5f * Hf;
        float x0 = floorf(x), y0 = floorf(y);
        sx0[lvl][pt] = x0;  sy0[lvl][pt] = y0;
        swx1[lvl][pt] = x - x0;  swy1[lvl][pt] = y - y0;
        if (lvl == 0) sval[pt] = (z > 0.f) ? 1.f : 0.f;
    }
    __syncthreads();

    float cnt = 0.f;
    #pragma unroll
    for (int i = 0; i < 24; ++i) cnt += sval[i];
    cnt = fmaxf(cnt, 1.f);
    float icnt = 1.f / cnt;

    const int xi = t & 1;
    const int cb = t >> 1;
    const float xif = (float)xi;
    float acc0 = 0.f, acc1 = 0.f;

    #pragma unroll
    for (int lvl = 0; lvl < 2; ++lvl) {
        const int H = lvl ? 32 : 64;
        const int W = lvl ? 88 : 176;
        const int HW = H * W;
        const float* fm = lvl ? f1 : f0;

        float a0 = 0.f, a1 = 0.f;
        for (int i = 0; i < 24; ++i) {
            if (sval[i] == 0.f) continue;
            int v = i >> 2;
            float x0 = sx0[lvl][i], y0 = sy0[lvl][i];
            float wx1v = swx1[lvl][i], wy1v = swy1[lvl][i];
            float xw = xi ? wx1v : (1.f - wx1v);
            float wy0v = 1.f - wy1v;
            float xf = x0 + xif;
            if (!(xf >= 0.f && xf <= (float)(W - 1))) continue;
            int xc = (int)xf;
            const float* bse  = fm + ((size_t)(b * V + v) * C + cb) * (size_t)HW;
            const float* bse2 = bse + (size_t)128 * HW;
            if (y0 >= 0.f && y0 <= (float)(H - 1)) {
                int off = (int)y0 * W + xc;
                float pw = xw * wy0v;
                a0 += bse[off]  * pw;
                a1 += bse2[off] * pw;
            }
            float y1 = y0 + 1.f;
            if (y1 >= 0.f && y1 <= (float)(H - 1)) {
                int off = (int)y1 * W + xc;
                float pw = xw * wy1v;
                a0 += bse[off]  * pw;
                a1 += bse2[off] * pw;
            }
        }
        acc0 += a0 * icnt;
        acc1 += a1 * icnt;
    }
    acc0 *= 0.5f; acc1 *= 0.5f;
    acc0 += __shfl_xor(acc0, 1);
    acc1 += __shfl_xor(acc1, 1);
    float* outp = sampled + (size_t)(b * Q + q) * C;
    if (xi == 0) outp[cb] = acc0;
    else         outp[cb + 128] = acc1;
}

// MFMA GEMM, BM=32/BN=64, 128 threads (2 waves). K/V projections.
__global__ __launch_bounds__(128)
void gemm_kv32(const float* __restrict__ Xs,
               const float* __restrict__ Wk, const float* __restrict__ Wv,
               const float* __restrict__ bk, const float* __restrict__ bv,
               float* __restrict__ Yk, float* __restrict__ Yv)
{
    __shared__ __align__(16) short As[32][264];
    const int z = blockIdx.z;
    const float* W    = z ? Wv : Wk;
    const float* bias = z ? bv : bk;
    float* Y          = z ? Yv : Yk;
    const int m0 = blockIdx.x * 32, n0t = blockIdx.y;

    const int tid = threadIdx.x;
    const int lane = tid & 63, w = tid >> 6;
    const int l15 = lane & 15, g = lane >> 4;

    {
        int r = tid & 31, part = tid >> 5;   // part 0..3 covers k = part*64..+63
        int gm = m0 + r;
        #pragma unroll
        for (int c = 0; c < 8; ++c) {
            int k = part * 64 + c * 8;
            float4 x = make_float4(0.f, 0.f, 0.f, 0.f);
            float4 y = make_float4(0.f, 0.f, 0.f, 0.f);
            if (gm < M_ROWS) {
                x = *(const float4*)(Xs + (size_t)gm * C + k);
                y = *(const float4*)(Xs + (size_t)gm * C + k + 4);
            }
            short8 s;
            s[0] = f2bf(x.x); s[1] = f2bf(x.y); s[2] = f2bf(x.z); s[3] = f2bf(x.w);
            s[4] = f2bf(y.x); s[5] = f2bf(y.y); s[6] = f2bf(y.z); s[7] = f2bf(y.w);
            *(short8*)&As[r][k] = s;
        }
    }
    __syncthreads();

    f32x4 acc[4];
    #pragma unroll
    for (int c = 0; c < 4; ++c) acc[c] = (f32x4){0.f, 0.f, 0.f, 0.f};

    #pragma unroll
    for (int ks = 0; ks < 8; ++ks) {
        short8 af = *(const short8*)&As[16 * w + l15][ks * 32 + 8 * g];
        #pragma unroll
        for (int c = 0; c < 4; ++c) {
            int nt = n0t * 4 + c;
            short8 bf = loadWfrag(W, nt * 16 + l15, ks * 32 + 8 * g);
            acc[c] = __builtin_amdgcn_mfma_f32_16x16x32_bf16(af, bf, acc[c], 0, 0, 0);
        }
    }

    #pragma unroll
    for (int c = 0; c < 4; ++c) {
        int n = n0t * 64 + c * 16 + l15;
        float bv4 = bias[n];
        #pragma unroll
        for (int j = 0; j < 4; ++j) {
            int gm = m0 + 16 * w + 4 * g + j;
            if (gm < M_ROWS) Y[(size_t)gm * C + n] = acc[c][j] + bv4;
        }
    }
}

// O-projection, BM=32/BN=32, 128 threads, with 8-way split-K merge fused
// into A-staging.
__global__ __launch_bounds__(128)
void gemm_o_merge32(const float* __restrict__ Opart, const float2* __restrict__ ml,
                    const float* __restrict__ Wo, const float* __restrict__ bias,
                    float* __restrict__ Y)
{
    __shared__ __align__(16) short As[32][264];
    const int tid = threadIdx.x;
    const int lane = tid & 63, w = tid >> 6;
    const int l15 = lane & 15, g = lane >> 4;
    const int m0 = blockIdx.x * 32, n0t = blockIdx.y;

    {
        int r = tid & 31, part = tid >> 5;   // part -> heads {2p, 2p+1}
        int gm = m0 + r;
        if (gm < M_ROWS) {
            int bb = (gm >= Q) ? 1 : 0;
            int qq = gm - bb * Q;
            #pragma unroll
            for (int hh = 0; hh < 2; ++hh) {
                int h = 2 * part + hh;
                int rrow = (bb * NH + h) * Q + qq;
                float2 v[SPLITS];
                float m = -1e30f;
                #pragma unroll
                for (int s = 0; s < SPLITS; ++s) {
                    v[s] = ml[(size_t)s * RBH + rrow];
                    m = fmaxf(m, v[s].x);
                }
                float l = 0.f, wgt[SPLITS];
                #pragma unroll
                for (int s = 0; s < SPLITS; ++s) {
                    wgt[s] = __expf(v[s].x - m);
                    l += v[s].y * wgt[s];
                }
                float invl = 1.f / l;
                #pragma unroll
                for (int cc = 0; cc < 4; ++cc) {
                    int d0 = cc * 8;
                    float o[8] = {0.f,0.f,0.f,0.f,0.f,0.f,0.f,0.f};
                    #pragma unroll
                    for (int s = 0; s < SPLITS; ++s) {
                        const float* op = Opart + ((size_t)s * RBH + rrow) * 32 + d0;
                        float4 x = *(const float4*)op;
                        float4 y = *(const float4*)(op + 4);
                        o[0] += x.x * wgt[s]; o[1] += x.y * wgt[s];
                        o[2] += x.z * wgt[s]; o[3] += x.w * wgt[s];
                        o[4] += y.x * wgt[s]; o[5] += y.y * wgt[s];
                        o[6] += y.z * wgt[s]; o[7] += y.w * wgt[s];
                    }
                    short8 sv;
                    #pragma unroll
                    for (int j = 0; j < 8; ++j) sv[j] = f2bf(o[j] * invl);
                    *(short8*)&As[r][part * 64 + hh * 32 + d0] = sv;
                }
            }
        } else {
            #pragma unroll
            for (int c = 0; c < 8; ++c) {
                short8 zz = {0,0,0,0,0,0,0,0};
                *(short8*)&As[r][part * 64 + c * 8] = zz;
            }
        }
    }
    __syncthreads();

    f32x4 acc[2];
    acc[0] = (f32x4){0.f, 0.f, 0.f, 0.f};
    acc[1] = (f32x4){0.f, 0.f, 0.f, 0.f};

    #pragma unroll
    for (int ks = 0; ks < 8; ++ks) {
        short8 af = *(const short8*)&As[16 * w + l15][ks * 32 + 8 * g];
        #pragma unroll
        for (int c = 0; c < 2; ++c) {
            int nt = n0t * 2 + c;
            short8 bf = loadWfrag(Wo, nt * 16 + l15, ks * 32 + 8 * g);
            acc[c] = __builtin_amdgcn_mfma_f32_16x16x32_bf16(af, bf, acc[c], 0, 0, 0);
        }
    }

    #pragma unroll
    for (int c = 0; c < 2; ++c) {
        int n = n0t * 32 + c * 16 + l15;
        float bv = bias[n];
        #pragma unroll
        for (int j = 0; j < 4; ++j) {
            int gm = m0 + 16 * w + 4 * g + j;
            if (gm < M_ROWS) Y[(size_t)gm * C + n] = acc[c][j] + bv;
        }
    }
}

// Split-K MFMA flash attention. blockIdx.z = b*SPLITS + s (8 splits, TPS=4).
__global__ __launch_bounds__(128)
void attn_mfma_split(const float* __restrict__ qb, const float* __restrict__ kb,
                     const float* __restrict__ vb,
                     float* __restrict__ Opart, float2* __restrict__ ml)
{
    __shared__ __align__(16) short Ks[2][32][40];   // [buf][key][dim]
    __shared__ __align__(16) short VT[2][32][36];   // [buf][dim][key]

    const int tid = threadIdx.x;
    const int lane = tid & 63;
    const int w = tid >> 6;
    const int l15 = lane & 15, g = lane >> 4;
    const int bz = blockIdx.z;
    const int b = bz >> 3, s = bz & 7;
    const int h = blockIdx.y;
    const int q0 = blockIdx.x * 32 + w * 16;
    const int t0 = s * TPS;
    const int t1 = (t0 + TPS < NT) ? (t0 + TPS) : NT;

    short8 qf;
    {
        const float sc = 0.17677669529663687f; // 1/sqrt(32)
        int qrow = q0 + l15;
        float4 a = make_float4(0.f,0.f,0.f,0.f), c2 = make_float4(0.f,0.f,0.f,0.f);
        if (qrow < Q) {
            const float* p = qb + (size_t)(b * Q + qrow) * C + h * HD + 8 * g;
            a  = *(const float4*)p;
            c2 = *(const float4*)(p + 4);
        }
        qf[0]=f2bf(a.x*sc);  qf[1]=f2bf(a.y*sc);  qf[2]=f2bf(a.z*sc);  qf[3]=f2bf(a.w*sc);
        qf[4]=f2bf(c2.x*sc); qf[5]=f2bf(c2.y*sc); qf[6]=f2bf(c2.z*sc); qf[7]=f2bf(c2.w*sc);
    }

    float m_ = -1e30f, l_ = 0.f;
    f32x4 acc0 = {0.f,0.f,0.f,0.f}, acc1 = {0.f,0.f,0.f,0.f};
    const f32x4 z4 = {0.f,0.f,0.f,0.f};

    const int keyA = tid >> 3,        ccA = tid & 7;
    const int keyB = (128 + tid) >> 3, ccB = tid & 7;
    float4 kregA, vregA, kregB, vregB;

    #define LOAD_TILE(t)                                                        \
    {                                                                           \
        int gkA = (t) * 32 + keyA, gkB = (t) * 32 + keyB;                       \
        if (gkA < Q) {                                                          \
            const float* kp = kb + (size_t)(b*Q+gkA)*C + h*HD + 4*ccA;          \
            const float* vp = vb + (size_t)(b*Q+gkA)*C + h*HD + 4*ccA;          \
            kregA = *(const float4*)kp; vregA = *(const float4*)vp;             \
        } else { kregA = make_float4(0.f,0.f,0.f,0.f); vregA = kregA; }         \
        if (gkB < Q) {                                                          \
            const float* kp = kb + (size_t)(b*Q+gkB)*C + h*HD + 4*ccB;          \
            const float* vp = vb + (size_t)(b*Q+gkB)*C + h*HD + 4*ccB;          \
            kregB = *(const float4*)kp; vregB = *(const float4*)vp;             \
        } else { kregB = make_float4(0.f,0.f,0.f,0.f); vregB = kregB; }         \
    }

    #define WRITE_LDS(bi)                                                       \
    {                                                                           \
        short4 ks;                                                              \
        ks.x = f2bf(kregA.x); ks.y = f2bf(kregA.y); ks.z = f2bf(kregA.z); ks.w = f2bf(kregA.w); \
        *(short4*)&Ks[bi][keyA][4 * ccA] = ks;                                  \
        VT[bi][4*ccA+0][keyA] = f2bf(vregA.x);                                  \
        VT[bi][4*ccA+1][keyA] = f2bf(vregA.y);                                  \
        VT[bi][4*ccA+2][keyA] = f2bf(vregA.z);                                  \
        VT[bi][4*ccA+3][keyA] = f2bf(vregA.w);                                  \
        ks.x = f2bf(kregB.x); ks.y = f2bf(kregB.y); ks.z = f2bf(kregB.z); ks.w = f2bf(kregB.w); \
        *(short4*)&Ks[bi][keyB][4 * ccB] = ks;                                  \
        VT[bi][4*ccB+0][keyB] = f2bf(vregB.x);                                  \
        VT[bi][4*ccB+1][keyB] = f2bf(vregB.y);                                  \
        VT[bi][4*ccB+2][keyB] = f2bf(vregB.z);                                  \
        VT[bi][4*ccB+3][keyB] = f2bf(vregB.w);                                  \
    }

    LOAD_TILE(t0);
    WRITE_LDS(0);
    __syncthreads();

    for (int t = t0; t < t1; ++t) {
        const int buf = (t - t0) & 1;
        if (t + 1 < t1) LOAD_TILE(t + 1);

        short8 kf0 = *(const short8*)&Ks[buf][l15][8 * g];
        short8 kf1 = *(const short8*)&Ks[buf][16 + l15][8 * g];
        f32x4 s0 = __builtin_amdgcn_mfma_f32_16x16x32_bf16(kf0, qf, z4, 0, 0, 0);
        f32x4 s1 = __builtin_amdgcn_mfma_f32_16x16x32_bf16(kf1, qf, z4, 0, 0, 0);

        const int kbase = t * 32;
        if (kbase + 32 > Q) {
            #pragma unroll
            for (int j = 0; j < 4; ++j) {
                if (kbase + 4 * g + j      >= Q) s0[j] = -1e30f;
                if (kbase + 16 + 4 * g + j >= Q) s1[j] = -1e30f;
            }
        }

        float tm = fmaxf(fmaxf(fmaxf(s0[0], s0[1]), fmaxf(s0[2], s0[3])),
                         fmaxf(fmaxf(s1[0], s1[1]), fmaxf(s1[2], s1[3])));
        tm = fmaxf(tm, __shfl_xor(tm, 16));
        tm = fmaxf(tm, __shfl_xor(tm, 32));
        float mn = fmaxf(m_, tm);
        float al = __expf(m_ - mn);
        m_ = mn;
        float p0 = __expf(s0[0]-mn), p1 = __expf(s0[1]-mn), p2 = __expf(s0[2]-mn), p3 = __expf(s0[3]-mn);
        float p4 = __expf(s1[0]-mn), p5 = __expf(s1[1]-mn), p6 = __expf(s1[2]-mn), p7 = __expf(s1[3]-mn);
        float ps = ((p0+p1)+(p2+p3)) + ((p4+p5)+(p6+p7));
        ps += __shfl_xor(ps, 16);
        ps += __shfl_xor(ps, 32);
        l_ = l_ * al + ps;

        #pragma unroll
        for (int j = 0; j < 4; ++j) {
            float alr = __shfl(al, 4 * g + j);
            acc0[j] *= alr;
            acc1[j] *= alr;
        }

        short8 pf;
        pf[0]=f2bf(p0); pf[1]=f2bf(p1); pf[2]=f2bf(p2); pf[3]=f2bf(p3);
        pf[4]=f2bf(p4); pf[5]=f2bf(p5); pf[6]=f2bf(p6); pf[7]=f2bf(p7);

        short4 va  = *(const short4*)&VT[buf][l15][4 * g];
        short4 vb2 = *(const short4*)&VT[buf][l15][16 + 4 * g];
        short4 vc  = *(const short4*)&VT[buf][16 + l15][4 * g];
        short4 vd  = *(const short4*)&VT[buf][16 + l15][16 + 4 * g];
        short8 vf0, vf1;
        vf0[0]=va.x;  vf0[1]=va.y;  vf0[2]=va.z;  vf0[3]=va.w;
        vf0[4]=vb2.x; vf0[5]=vb2.y; vf0[6]=vb2.z; vf0[7]=vb2.w;
        vf1[0]=vc.x;  vf1[1]=vc.y;  vf1[2]=vc.z;  vf1[3]=vc.w;
        vf1[4]=vd.x;  vf1[5]=vd.y;  vf1[6]=vd.z;  vf1[7]=vd.w;
        acc0 = __builtin_amdgcn_mfma_f32_16x16x32_bf16(pf, vf0, acc0, 0, 0, 0);
        acc1 = __builtin_amdgcn_mfma_f32_16x16x32_bf16(pf, vf1, acc1, 0, 0, 0);

        if (t + 1 < t1) WRITE_LDS(buf ^ 1);
        __syncthreads();
    }

    const size_t rowbase = (size_t)((s * B + b) * NH + h) * Q;
    float* op = Opart + rowbase * 32;
    #pragma unroll
    for (int j = 0; j < 4; ++j) {
        int qrow = q0 + 4 * g + j;
        if (qrow < Q) {
            op[(size_t)qrow * 32 + l15]      = acc0[j];
            op[(size_t)qrow * 32 + 16 + l15] = acc1[j];
        }
    }
    if (g == 0 && q0 + l15 < Q) ml[rowbase + q0 + l15] = make_float2(m_, l_);
    #undef LOAD_TILE
    #undef WRITE_LDS
}

extern "C" void kernel_launch(void* const* d_in, const int* in_sizes, int n_in,
                              void* d_out, int out_size, void* d_ws, size_t ws_size,
                              hipStream_t stream) {
    const float* f0   = (const float*)d_in[0];
    const float* f1   = (const float*)d_in[1];
    const float* refs = (const float*)d_in[2];
    const float* intr = (const float*)d_in[3];
    const float* extr = (const float*)d_in[4];
    const float* qin  = (const float*)d_in[5];
    const float* Wq   = (const float*)d_in[6];
    const float* bq   = (const float*)d_in[7];
    const float* Wk   = (const float*)d_in[8];
    const float* bk   = (const float*)d_in[9];
    const float* Wv   = (const float*)d_in[10];
    const float* bv   = (const float*)d_in[11];
    const float* Wo   = (const float*)d_in[12];
    const float* bo   = (const float*)d_in[13];

    float* ws      = (float*)d_ws;
    float* sampled = ws;                  // 460800 each
    float* qbuf    = sampled + 460800;
    float* kbuf    = qbuf    + 460800;
    float* vbuf    = kbuf    + 460800;
    float* Opart   = vbuf + 460800;       // SPLITS*RBH*32 f32 = 3,686,400
    float2* ml     = (float2*)(Opart + (size_t)SPLITS * RBH * 32);
    float* out     = (float*)d_out;

    // K1: sampler (1800 blocks) + Q projection (116 blocks)
    sampler_qproj<<<B * Q + 116, 256, 0, stream>>>(f0, f1, refs, intr, extr,
                                                   sampled, qin, Wq, bq, qbuf);

    // K2: K,V projections (BM=32)
    dim3 kvgrid((M_ROWS + 31) / 32, C / 64, 2);
    gemm_kv32<<<kvgrid, 128, 0, stream>>>(sampled, Wk, Wv, bk, bv, kbuf, vbuf);

    // K3: split-K attention
    dim3 agrid((Q + 31) / 32, NH, B * SPLITS);
    attn_mfma_split<<<agrid, 128, 0, stream>>>(qbuf, kbuf, vbuf, Opart, ml);

    // K4: merge + O projection (BM=32, BN=32)
    dim3 ogrid((M_ROWS + 31) / 32, C / 32, 1);
    gemm_o_merge32<<<ogrid, 128, 0, stream>>>(Opart, ml, Wo, bo, out);
}

// Round 10
// 57.876 us; speedup vs baseline: 2.1979x; 2.1979x over previous
//
#include <hip/hip_runtime.h>
#include <math.h>

#define B 2
#define V 6
#define C 256
#define Q 900
#define NH 8
#define HD 32
#define RADIUS 2.0f
#define M_ROWS (B * Q)   // 1800
#define NT 29            // ceil(900/32) key tiles
#define SPLITS 4
#define TPS 8            // tiles per split (last split gets 5)
#define RBH (B * NH * Q) // 14400 rows per split

using short8 = __attribute__((ext_vector_type(8))) short;  // 8 bf16
using f32x4  = __attribute__((ext_vector_type(4))) float;

// f32 -> bf16 (RNE), bit pattern in a short
__device__ __forceinline__ short f2bf(float f) {
    union { float f; unsigned u; } x; x.f = f;
    unsigned r = x.u + 0x7fffu + ((x.u >> 16) & 1u);
    return (short)(r >> 16);
}

// keypoints: [0,0,0],[R,0,0],[0,R,0],[-R,0,0]
__device__ __forceinline__ float kpx(int k) { return (k == 1) ? RADIUS : ((k == 3) ? -RADIUS : 0.f); }
__device__ __forceinline__ float kpy(int k) { return (k == 2) ? RADIUS : 0.f; }

// Fused: blocks [0,1800) = sampler; blocks [1800,1928) = weight packing.
// Weight packing: W[n][k] fp32 -> bf16 B-fragment order
// P[((ks*16 + nt)*64 + lane)*8 + j] with n = nt*16+(lane&15), k = ks*32+8*(lane>>4)+j.
__global__ __launch_bounds__(256)
void sampler_wpack(const float* __restrict__ f0, const float* __restrict__ f1,
                   const float* __restrict__ refs, const float* __restrict__ intr,
                   const float* __restrict__ extr, float* __restrict__ sampled,
                   const float* __restrict__ W0, const float* __restrict__ W1,
                   const float* __restrict__ W2, const float* __restrict__ W3,
                   short* __restrict__ P0, short* __restrict__ P1,
                   short* __restrict__ P2, short* __restrict__ P3)
{
    const int bid = blockIdx.x;
    if (bid >= B * Q) {
        int gid = (bid - B * Q) * 256 + threadIdx.x;   // 32768 total
        int mat = gid >> 13;
        int rem = gid & 8191;
        int ks = rem >> 10;          // 0..7
        int nt = (rem >> 6) & 15;    // 0..15
        int lane = rem & 63;
        const float* W = (mat == 0) ? W0 : (mat == 1) ? W1 : (mat == 2) ? W2 : W3;
        short* P = (mat == 0) ? P0 : (mat == 1) ? P1 : (mat == 2) ? P2 : P3;
        int n = nt * 16 + (lane & 15);
        int k0 = ks * 32 + 8 * (lane >> 4);
        float4 a = *(const float4*)(W + (size_t)n * C + k0);
        float4 b = *(const float4*)(W + (size_t)n * C + k0 + 4);
        short8 s;
        s[0] = f2bf(a.x); s[1] = f2bf(a.y); s[2] = f2bf(a.z); s[3] = f2bf(a.w);
        s[4] = f2bf(b.x); s[5] = f2bf(b.y); s[6] = f2bf(b.z); s[7] = f2bf(b.w);
        *(short8*)(P + (size_t)((ks * 16 + nt) * 64 + lane) * 8) = s;
        return;
    }

    int b = bid / Q, q = bid % Q;
    int t = threadIdx.x;
    __shared__ float sx0[2][24], sy0[2][24], swx1[2][24], swy1[2][24];
    __shared__ float sval[24];

    if (t < 48) {
        int lvl = t / 24, pt = t % 24;
        int v = pt >> 2, kp = pt & 3;
        const float* r = refs + (size_t)(b * Q + q) * 3;
        float px = r[0] + kpx(kp), py = r[1] + kpy(kp), pz = r[2];
        const float* E = extr + (size_t)(b * V + v) * 16;
        float cx = E[0] * px + E[1] * py + E[2]  * pz + E[3];
        float cy = E[4] * px + E[5] * py + E[6]  * pz + E[7];
        float cz = E[8] * px + E[9] * py + E[10] * pz + E[11];
        const float* Km = intr + (size_t)(b * V + v) * 9;
        float u = Km[0] * cx + Km[1] * cy + Km[2] * cz;
        float w = Km[3] * cx + Km[4] * cy + Km[5] * cz;
        float z = Km[6] * cx + Km[7] * cy + Km[8] * cz;
        float zs = (fabsf(z) > 1e-6f) ? z : 1e-6f;
        float ru = u / zs, rv = w / zs;
        const float Wf = lvl ? 87.f : 175.f;   // W-1
        const float Hf = lvl ? 31.f : 63.f;    // H-1
        float gx = 2.f * ru / Wf - 1.f;
        float gy = 2.f * rv / Hf - 1.f;
        float x = (gx + 1.f) * 0.5f * Wf;
        float y = (gy + 1.f) * 0.5f * Hf;
        float x0 = floorf(x), y0 = floorf(y);
        sx0[lvl][pt] = x0;  sy0[lvl][pt] = y0;
        swx1[lvl][pt] = x - x0;  swy1[lvl][pt] = y - y0;
        if (lvl == 0) sval[pt] = (z > 0.f) ? 1.f : 0.f;
    }
    __syncthreads();

    float cnt = 0.f;
    #pragma unroll
    for (int i = 0; i < 24; ++i) cnt += sval[i];
    cnt = fmaxf(cnt, 1.f);
    float icnt = 1.f / cnt;

    const int xi = t & 1;
    const int cb = t >> 1;
    const float xif = (float)xi;
    float acc0 = 0.f, acc1 = 0.f;

    #pragma unroll
    for (int lvl = 0; lvl < 2; ++lvl) {
        const int H = lvl ? 32 : 64;
        const int W = lvl ? 88 : 176;
        const int HW = H * W;
        const float* fm = lvl ? f1 : f0;

        float a0 = 0.f, a1 = 0.f;
        for (int i = 0; i < 24; ++i) {
            if (sval[i] == 0.f) continue;
            int v = i >> 2;
            float x0 = sx0[lvl][i], y0 = sy0[lvl][i];
            float wx1v = swx1[lvl][i], wy1v = swy1[lvl][i];
            float xw = xi ? wx1v : (1.f - wx1v);
            float wy0v = 1.f - wy1v;
            float xf = x0 + xif;
            if (!(xf >= 0.f && xf <= (float)(W - 1))) continue;
            int xc = (int)xf;
            const float* bse  = fm + ((size_t)(b * V + v) * C + cb) * (size_t)HW;
            const float* bse2 = bse + (size_t)128 * HW;
            if (y0 >= 0.f && y0 <= (float)(H - 1)) {
                int off = (int)y0 * W + xc;
                float pw = xw * wy0v;
                a0 += bse[off]  * pw;
                a1 += bse2[off] * pw;
            }
            float y1 = y0 + 1.f;
            if (y1 >= 0.f && y1 <= (float)(H - 1)) {
                int off = (int)y1 * W + xc;
                float pw = xw * wy1v;
                a0 += bse[off]  * pw;
                a1 += bse2[off] * pw;
            }
        }
        acc0 += a0 * icnt;
        acc1 += a1 * icnt;
    }
    acc0 *= 0.5f; acc1 *= 0.5f;
    acc0 += __shfl_xor(acc0, 1);
    acc1 += __shfl_xor(acc1, 1);
    float* outp = sampled + (size_t)(b * Q + q) * C;
    if (xi == 0) outp[cb] = acc0;
    else         outp[cb + 128] = acc1;
}

// MFMA GEMM: Y[m][n] = sum_k A[m][k]*W[n][k] + bias[n]. Packed weights.
__device__ __forceinline__ void mgemm_body(const float* __restrict__ A,
                                           const short* __restrict__ Wp,
                                           const float* __restrict__ bias,
                                           float* __restrict__ Y,
                                           int m0, int n0t)
{
    __shared__ __align__(16) short As[64][264];
    const int tid = threadIdx.x;
    const int lane = tid & 63, w = tid >> 6;
    const int l15 = lane & 15, g = lane >> 4;

    {
        int r = tid & 63, part = tid >> 6;
        int gm = m0 + r;
        #pragma unroll
        for (int c = 0; c < 8; ++c) {
            int k = part * 64 + c * 8;
            float4 x = make_float4(0.f, 0.f, 0.f, 0.f);
            float4 y = make_float4(0.f, 0.f, 0.f, 0.f);
            if (gm < M_ROWS) {
                x = *(const float4*)(A + (size_t)gm * C + k);
                y = *(const float4*)(A + (size_t)gm * C + k + 4);
            }
            short8 s;
            s[0] = f2bf(x.x); s[1] = f2bf(x.y); s[2] = f2bf(x.z); s[3] = f2bf(x.w);
            s[4] = f2bf(y.x); s[5] = f2bf(y.y); s[6] = f2bf(y.z); s[7] = f2bf(y.w);
            *(short8*)&As[r][k] = s;
        }
    }
    __syncthreads();

    f32x4 acc[4];
    #pragma unroll
    for (int c = 0; c < 4; ++c) acc[c] = (f32x4){0.f, 0.f, 0.f, 0.f};

    #pragma unroll
    for (int ks = 0; ks < 8; ++ks) {
        short8 af = *(const short8*)&As[16 * w + l15][ks * 32 + 8 * g];
        #pragma unroll
        for (int c = 0; c < 4; ++c) {
            int nt = n0t * 4 + c;
            short8 bf = *(const short8*)(Wp + (size_t)((ks * 16 + nt) * 64 + lane) * 8);
            acc[c] = __builtin_amdgcn_mfma_f32_16x16x32_bf16(af, bf, acc[c], 0, 0, 0);
        }
    }

    #pragma unroll
    for (int c = 0; c < 4; ++c) {
        int n = n0t * 64 + c * 16 + l15;
        float bv = bias[n];
        #pragma unroll
        for (int j = 0; j < 4; ++j) {
            int gm = m0 + 16 * w + 4 * g + j;
            if (gm < M_ROWS) Y[(size_t)gm * C + n] = acc[c][j] + bv;
        }
    }
}

__global__ __launch_bounds__(256)
void gemm_qkv_mfma(const float* __restrict__ Xq, const float* __restrict__ Xs,
                   const short* __restrict__ Pq, const short* __restrict__ Pk,
                   const short* __restrict__ Pv,
                   const float* __restrict__ bq, const float* __restrict__ bk,
                   const float* __restrict__ bv,
                   float* __restrict__ Yq, float* __restrict__ Yk, float* __restrict__ Yv)
{
    int z = blockIdx.z;
    const float* A    = (z == 0) ? Xq : Xs;
    const short* Wp   = (z == 0) ? Pq : (z == 1) ? Pk : Pv;
    const float* bias = (z == 0) ? bq : (z == 1) ? bk : bv;
    float* Y          = (z == 0) ? Yq : (z == 1) ? Yk : Yv;
    mgemm_body(A, Wp, bias, Y, blockIdx.x * 64, blockIdx.y);
}

// O-projection with the split-K attention merge fused into A-staging.
__global__ __launch_bounds__(256)
void gemm_o_merge(const float* __restrict__ Opart, const float2* __restrict__ ml,
                  const short* __restrict__ Wp, const float* __restrict__ bias,
                  float* __restrict__ Y)
{
    __shared__ __align__(16) short As[64][264];
    const int tid = threadIdx.x;
    const int lane = tid & 63, w = tid >> 6;
    const int l15 = lane & 15, g = lane >> 4;
    const int m0 = blockIdx.x * 64, n0t = blockIdx.y;

    {
        int r = tid & 63, part = tid >> 6;
        int gm = m0 + r;
        if (gm < M_ROWS) {
            int bb = (gm >= Q) ? 1 : 0;
            int qq = gm - bb * Q;
            #pragma unroll
            for (int hh = 0; hh < 2; ++hh) {
                int h = 2 * part + hh;
                int rrow = (bb * NH + h) * Q + qq;
                float2 v[SPLITS];
                float m = -1e30f;
                #pragma unroll
                for (int s = 0; s < SPLITS; ++s) {
                    v[s] = ml[(size_t)s * RBH + rrow];
                    m = fmaxf(m, v[s].x);
                }
                float l = 0.f, wgt[SPLITS];
                #pragma unroll
                for (int s = 0; s < SPLITS; ++s) {
                    wgt[s] = __expf(v[s].x - m);
                    l += v[s].y * wgt[s];
                }
                float invl = 1.f / l;
                #pragma unroll
                for (int cc = 0; cc < 4; ++cc) {
                    int d0 = cc * 8;
                    float o[8] = {0.f,0.f,0.f,0.f,0.f,0.f,0.f,0.f};
                    #pragma unroll
                    for (int s = 0; s < SPLITS; ++s) {
                        const float* op = Opart + ((size_t)s * RBH + rrow) * 32 + d0;
                        float4 x = *(const float4*)op;
                        float4 y = *(const float4*)(op + 4);
                        o[0] += x.x * wgt[s]; o[1] += x.y * wgt[s];
                        o[2] += x.z * wgt[s]; o[3] += x.w * wgt[s];
                        o[4] += y.x * wgt[s]; o[5] += y.y * wgt[s];
                        o[6] += y.z * wgt[s]; o[7] += y.w * wgt[s];
                    }
                    short8 sv;
                    #pragma unroll
                    for (int j = 0; j < 8; ++j) sv[j] = f2bf(o[j] * invl);
                    *(short8*)&As[r][part * 64 + hh * 32 + d0] = sv;
                }
            }
        } else {
            #pragma unroll
            for (int c = 0; c < 8; ++c) {
                short8 z = {0,0,0,0,0,0,0,0};
                *(short8*)&As[r][part * 64 + c * 8] = z;
            }
        }
    }
    __syncthreads();

    f32x4 acc[4];
    #pragma unroll
    for (int c = 0; c < 4; ++c) acc[c] = (f32x4){0.f, 0.f, 0.f, 0.f};

    #pragma unroll
    for (int ks = 0; ks < 8; ++ks) {
        short8 af = *(const short8*)&As[16 * w + l15][ks * 32 + 8 * g];
        #pragma unroll
        for (int c = 0; c < 4; ++c) {
            int nt = n0t * 4 + c;
            short8 bf = *(const short8*)(Wp + (size_t)((ks * 16 + nt) * 64 + lane) * 8);
            acc[c] = __builtin_amdgcn_mfma_f32_16x16x32_bf16(af, bf, acc[c], 0, 0, 0);
        }
    }

    #pragma unroll
    for (int c = 0; c < 4; ++c) {
        int n = n0t * 64 + c * 16 + l15;
        float bv = bias[n];
        #pragma unroll
        for (int j = 0; j < 4; ++j) {
            int gm = m0 + 16 * w + 4 * g + j;
            if (gm < M_ROWS) Y[(size_t)gm * C + n] = acc[c][j] + bv;
        }
    }
}

// Split-K MFMA flash attention (round-8 proven: SPLITS=4, TPS=8, dbuf LDS).
__global__ __launch_bounds__(128)
void attn_mfma_split(const float* __restrict__ qb, const float* __restrict__ kb,
                     const float* __restrict__ vb,
                     float* __restrict__ Opart, float2* __restrict__ ml)
{
    __shared__ __align__(16) short Ks[2][32][40];   // [buf][key][dim]
    __shared__ __align__(16) short VT[2][32][36];   // [buf][dim][key]

    const int tid = threadIdx.x;
    const int lane = tid & 63;
    const int w = tid >> 6;
    const int l15 = lane & 15, g = lane >> 4;
    const int bz = blockIdx.z;
    const int b = bz >> 2, s = bz & 3;
    const int h = blockIdx.y;
    const int q0 = blockIdx.x * 32 + w * 16;
    const int t0 = s * TPS;
    const int t1 = (t0 + TPS < NT) ? (t0 + TPS) : NT;

    short8 qf;
    {
        const float sc = 0.17677669529663687f; // 1/sqrt(32)
        int qrow = q0 + l15;
        float4 a = make_float4(0.f,0.f,0.f,0.f), c2 = make_float4(0.f,0.f,0.f,0.f);
        if (qrow < Q) {
            const float* p = qb + (size_t)(b * Q + qrow) * C + h * HD + 8 * g;
            a  = *(const float4*)p;
            c2 = *(const float4*)(p + 4);
        }
        qf[0]=f2bf(a.x*sc);  qf[1]=f2bf(a.y*sc);  qf[2]=f2bf(a.z*sc);  qf[3]=f2bf(a.w*sc);
        qf[4]=f2bf(c2.x*sc); qf[5]=f2bf(c2.y*sc); qf[6]=f2bf(c2.z*sc); qf[7]=f2bf(c2.w*sc);
    }

    float m_ = -1e30f, l_ = 0.f;
    f32x4 acc0 = {0.f,0.f,0.f,0.f}, acc1 = {0.f,0.f,0.f,0.f};
    const f32x4 z4 = {0.f,0.f,0.f,0.f};

    const int keyA = tid >> 3,        ccA = tid & 7;
    const int keyB = (128 + tid) >> 3, ccB = tid & 7;
    float4 kregA, vregA, kregB, vregB;

    #define LOAD_TILE(t)                                                        \
    {                                                                           \
        int gkA = (t) * 32 + keyA, gkB = (t) * 32 + keyB;                       \
        if (gkA < Q) {                                                          \
            const float* kp = kb + (size_t)(b*Q+gkA)*C + h*HD + 4*ccA;          \
            const float* vp = vb + (size_t)(b*Q+gkA)*C + h*HD + 4*ccA;          \
            kregA = *(const float4*)kp; vregA = *(const float4*)vp;             \
        } else { kregA = make_float4(0.f,0.f,0.f,0.f); vregA = kregA; }         \
        if (gkB < Q) {                                                          \
            const float* kp = kb + (size_t)(b*Q+gkB)*C + h*HD + 4*ccB;          \
            const float* vp = vb + (size_t)(b*Q+gkB)*C + h*HD + 4*ccB;          \
            kregB = *(const float4*)kp; vregB = *(const float4*)vp;             \
        } else { kregB = make_float4(0.f,0.f,0.f,0.f); vregB = kregB; }         \
    }

    #define WRITE_LDS(bi)                                                       \
    {                                                                           \
        short4 ks;                                                              \
        ks.x = f2bf(kregA.x); ks.y = f2bf(kregA.y); ks.z = f2bf(kregA.z); ks.w = f2bf(kregA.w); \
        *(short4*)&Ks[bi][keyA][4 * ccA] = ks;                                  \
        VT[bi][4*ccA+0][keyA] = f2bf(vregA.x);                                  \
        VT[bi][4*ccA+1][keyA] = f2bf(vregA.y);                                  \
        VT[bi][4*ccA+2][keyA] = f2bf(vregA.z);                                  \
        VT[bi][4*ccA+3][keyA] = f2bf(vregA.w);                                  \
        ks.x = f2bf(kregB.x); ks.y = f2bf(kregB.y); ks.z = f2bf(kregB.z); ks.w = f2bf(kregB.w); \
        *(short4*)&Ks[bi][keyB][4 * ccB] = ks;                                  \
        VT[bi][4*ccB+0][keyB] = f2bf(vregB.x);                                  \
        VT[bi][4*ccB+1][keyB] = f2bf(vregB.y);                                  \
        VT[bi][4*ccB+2][keyB] = f2bf(vregB.z);                                  \
        VT[bi][4*ccB+3][keyB] = f2bf(vregB.w);                                  \
    }

    LOAD_TILE(t0);
    WRITE_LDS(0);
    __syncthreads();

    for (int t = t0; t < t1; ++t) {
        const int buf = (t - t0) & 1;
        if (t + 1 < t1) LOAD_TILE(t + 1);

        short8 kf0 = *(const short8*)&Ks[buf][l15][8 * g];
        short8 kf1 = *(const short8*)&Ks[buf][16 + l15][8 * g];
        f32x4 s0 = __builtin_amdgcn_mfma_f32_16x16x32_bf16(kf0, qf, z4, 0, 0, 0);
        f32x4 s1 = __builtin_amdgcn_mfma_f32_16x16x32_bf16(kf1, qf, z4, 0, 0, 0);

        const int kbase = t * 32;
        if (kbase + 32 > Q) {
            #pragma unroll
            for (int j = 0; j < 4; ++j) {
                if (kbase + 4 * g + j      >= Q) s0[j] = -1e30f;
                if (kbase + 16 + 4 * g + j >= Q) s1[j] = -1e30f;
            }
        }

        float tm = fmaxf(fmaxf(fmaxf(s0[0], s0[1]), fmaxf(s0[2], s0[3])),
                         fmaxf(fmaxf(s1[0], s1[1]), fmaxf(s1[2], s1[3])));
        tm = fmaxf(tm, __shfl_xor(tm, 16));
        tm = fmaxf(tm, __shfl_xor(tm, 32));
        float mn = fmaxf(m_, tm);
        float al = __expf(m_ - mn);
        m_ = mn;
        float p0 = __expf(s0[0]-mn), p1 = __expf(s0[1]-mn), p2 = __expf(s0[2]-mn), p3 = __expf(s0[3]-mn);
        float p4 = __expf(s1[0]-mn), p5 = __expf(s1[1]-mn), p6 = __expf(s1[2]-mn), p7 = __expf(s1[3]-mn);
        float ps = ((p0+p1)+(p2+p3)) + ((p4+p5)+(p6+p7));
        ps += __shfl_xor(ps, 16);
        ps += __shfl_xor(ps, 32);
        l_ = l_ * al + ps;

        #pragma unroll
        for (int j = 0; j < 4; ++j) {
            float alr = __shfl(al, 4 * g + j);
            acc0[j] *= alr;
            acc1[j] *= alr;
        }

        short8 pf;
        pf[0]=f2bf(p0); pf[1]=f2bf(p1); pf[2]=f2bf(p2); pf[3]=f2bf(p3);
        pf[4]=f2bf(p4); pf[5]=f2bf(p5); pf[6]=f2bf(p6); pf[7]=f2bf(p7);

        short4 va  = *(const short4*)&VT[buf][l15][4 * g];
        short4 vb2 = *(const short4*)&VT[buf][l15][16 + 4 * g];
        short4 vc  = *(const short4*)&VT[buf][16 + l15][4 * g];
        short4 vd  = *(const short4*)&VT[buf][16 + l15][16 + 4 * g];
        short8 vf0, vf1;
        vf0[0]=va.x;  vf0[1]=va.y;  vf0[2]=va.z;  vf0[3]=va.w;
        vf0[4]=vb2.x; vf0[5]=vb2.y; vf0[6]=vb2.z; vf0[7]=vb2.w;
        vf1[0]=vc.x;  vf1[1]=vc.y;  vf1[2]=vc.z;  vf1[3]=vc.w;
        vf1[4]=vd.x;  vf1[5]=vd.y;  vf1[6]=vd.z;  vf1[7]=vd.w;
        acc0 = __builtin_amdgcn_mfma_f32_16x16x32_bf16(pf, vf0, acc0, 0, 0, 0);
        acc1 = __builtin_amdgcn_mfma_f32_16x16x32_bf16(pf, vf1, acc1, 0, 0, 0);

        if (t + 1 < t1) WRITE_LDS(buf ^ 1);
        __syncthreads();
    }

    const size_t rowbase = (size_t)((s * B + b) * NH + h) * Q;
    float* op = Opart + rowbase * 32;
    #pragma unroll
    for (int j = 0; j < 4; ++j) {
        int qrow = q0 + 4 * g + j;
        if (qrow < Q) {
            op[(size_t)qrow * 32 + l15]      = acc0[j];
            op[(size_t)qrow * 32 + 16 + l15] = acc1[j];
        }
    }
    if (g == 0 && q0 + l15 < Q) ml[rowbase + q0 + l15] = make_float2(m_, l_);
    #undef LOAD_TILE
    #undef WRITE_LDS
}

extern "C" void kernel_launch(void* const* d_in, const int* in_sizes, int n_in,
                              void* d_out, int out_size, void* d_ws, size_t ws_size,
                              hipStream_t stream) {
    const float* f0   = (const float*)d_in[0];
    const float* f1   = (const float*)d_in[1];
    const float* refs = (const float*)d_in[2];
    const float* intr = (const float*)d_in[3];
    const float* extr = (const float*)d_in[4];
    const float* qin  = (const float*)d_in[5];
    const float* Wq   = (const float*)d_in[6];
    const float* bq   = (const float*)d_in[7];
    const float* Wk   = (const float*)d_in[8];
    const float* bk   = (const float*)d_in[9];
    const float* Wv   = (const float*)d_in[10];
    const float* bv   = (const float*)d_in[11];
    const float* Wo   = (const float*)d_in[12];
    const float* bo   = (const float*)d_in[13];

    float* ws      = (float*)d_ws;
    float* sampled = ws;                  // 460800 each
    float* qbuf    = sampled + 460800;
    float* kbuf    = qbuf    + 460800;
    float* vbuf    = kbuf    + 460800;
    short* Pq      = (short*)(vbuf + 460800);   // 65536 bf16 each
    short* Pk      = Pq + 65536;
    short* Pv      = Pk + 65536;
    short* Po      = Pv + 65536;
    float* Opart   = (float*)(Po + 65536);      // SPLITS*RBH*32 f32
    float2* ml     = (float2*)(Opart + (size_t)SPLITS * RBH * 32);
    float* out     = (float*)d_out;

    // K1: sampler (1800 blocks) + weight packing (128 blocks)
    sampler_wpack<<<B * Q + 128, 256, 0, stream>>>(f0, f1, refs, intr, extr, sampled,
                                                   Wq, Wk, Wv, Wo, Pq, Pk, Pv, Po);

    // K2: Q/K/V projections (BM=64, packed weights)
    dim3 ggrid((M_ROWS + 63) / 64, C / 64, 3);
    gemm_qkv_mfma<<<ggrid, 256, 0, stream>>>(qin, sampled, Pq, Pk, Pv,
                                             bq, bk, bv, qbuf, kbuf, vbuf);

    // K3: split-K attention (SPLITS=4)
    dim3 agrid((Q + 31) / 32, NH, B * SPLITS);
    attn_mfma_split<<<agrid, 128, 0, stream>>>(qbuf, kbuf, vbuf, Opart, ml);

    // K4: merge + O projection (BM=64, packed weights)
    dim3 ogrid((M_ROWS + 63) / 64, C / 64, 1);
    gemm_o_merge<<<ogrid, 256, 0, stream>>>(Opart, ml, Po, bo, out);
}